// Round 6
// baseline (385.432 us; speedup 1.0000x reference)
//
#include <hip/hip_runtime.h>
#include <hip/hip_cooperative_groups.h>
#include <cstddef>
#include <cstdint>

namespace cg = cooperative_groups;

// Problem constants (match reference setup_inputs)
#define HH    128
#define WW    128
#define CC    392           // K*K*8 = 49*8
#define NPIX  (HH*WW)       // 16384
#define NROI  2048
#define PSK   7
#define NBIN  49
#define LAMDA 0.1f

// Layouts
#define CPAD    448         // input channels padded to 7*64
#define HPAD    130         // 128 + 1px zero halo each side
#define BKK     64          // K-chunk (A panel width)
#define ATH     (136*BKK)   // A panel: 136 rows (130 used) x 64 halves = 17408 B
// B fragment-major: Btf[((seg*7+kc)*2+kh)][cob(25)][quad(4)][fr(16)][8]
#define BKHS    12800       // halves per (seg,kc,kh) slice = 25*4*128
#define BTFH    (9*7*2*BKHS)

// grid: 1536 blocks x 256 threads; 12 jobs/row: 9 fat (3 ks x 3 col) + 3 thin
#define NBLK    1536
#define NTHR    256
#define GSTRIDE (NBLK*NTHR)
#define FTOT    (HPAD*HPAD*(CPAD/8))    // 946400 feature half8-groups
#define WTILES  (9*14*13)               // 1638 weight 32x32 tiles
#define POOL8   (NROI*NBIN*8)           // 802816

typedef _Float16 half8   __attribute__((ext_vector_type(8)));
typedef _Float16 half2v  __attribute__((ext_vector_type(2)));
typedef float    floatx4 __attribute__((ext_vector_type(4)));

// ---------------------------------------------------------------------------
// async global->LDS 16B (dest = wave-uniform base + lane*16)
// ---------------------------------------------------------------------------
__device__ __forceinline__ void async_ld16(const _Float16* g, _Float16* l) {
  __builtin_amdgcn_global_load_lds((const __attribute__((address_space(1))) void*)g,
                                   (__attribute__((address_space(3))) void*)l,
                                   16, 0, 0);
}

// ---------------------------------------------------------------------------
// Prep 1: features fp32 [128,128,392] -> f16 [130,130,448] halo+pad (grid-stride)
// ---------------------------------------------------------------------------
__device__ __forceinline__ void prep_features(const float* __restrict__ F,
                                              _Float16* __restrict__ Fh,
                                              int gtid, int stride) {
  for (int idx = gtid; idx < FTOT; idx += stride) {
    const int p   = idx / (CPAD / 8);
    const int cgi = idx - p * (CPAD / 8);
    const int c   = cgi * 8;
    const int py  = p / HPAD;
    const int px  = p - py * HPAD;
    half8 h;
#pragma unroll
    for (int i = 0; i < 8; ++i) h[i] = (_Float16)0.f;
    if (py >= 1 && py <= HH && px >= 1 && px <= WW && c < CC) {
      const float* src = F + ((size_t)(py - 1) * WW + (px - 1)) * CC + c;
      const float4 v0 = *(const float4*)src;
      const float4 v1 = *(const float4*)(src + 4);
      h[0] = (_Float16)v0.x; h[1] = (_Float16)v0.y;
      h[2] = (_Float16)v0.z; h[3] = (_Float16)v0.w;
      h[4] = (_Float16)v1.x; h[5] = (_Float16)v1.y;
      h[6] = (_Float16)v1.z; h[7] = (_Float16)v1.w;
    }
    *(half8*)(Fh + (size_t)p * CPAD + c) = h;
  }
}

// ---------------------------------------------------------------------------
// Prep 2: weights fp32 [9,392,392] (seg,ci,co) -> f16 fragment-major Btf via
// 32x32 LDS tile transpose (R4-verified). co zero-padded to 400.
// ---------------------------------------------------------------------------
__device__ __forceinline__ void prep_weights(const float* __restrict__ Wt,
                                             _Float16* __restrict__ Btf,
                                             float (*tile)[33],
                                             int bid, int t, int bdim, int nblocks) {
  for (int tl = bid; tl < WTILES; tl += nblocks) {
    const int seg = tl / (14 * 13);
    const int rem = tl - seg * (14 * 13);
    const int cit = rem / 13;         // ci tile 0..13
    const int cot = rem - cit * 13;   // co tile 0..12
    const int ci0 = cit * 32, co0 = cot * 32;
    __syncthreads();                  // protect tile reuse across iterations
    for (int idx = t; idx < 1024; idx += bdim) {
      const int lr = idx >> 5;        // local ci
      const int lc = idx & 31;        // local co (fast -> coalesced read)
      const int ci = ci0 + lr, co = co0 + lc;
      float v = 0.f;
      if (ci < CC && co < CC) v = Wt[((size_t)seg * CC + ci) * CC + co];
      tile[lr][lc] = v;
    }
    __syncthreads();
    for (int u = t; u < 128; u += bdim) {
      const int lr  = u & 31;         // local co
      const int lc8 = u >> 5;         // ci octet within tile
      const int co = co0 + lr;
      if (co < 400) {
        const int cib = ci0 + lc8 * 8;
        const int kc = cib >> 6, kh = (cib >> 5) & 1, qd = (cib >> 3) & 3;
        half8 v;
#pragma unroll
        for (int e = 0; e < 8; ++e) v[e] = (_Float16)tile[lc8 * 8 + e][lr];
        const size_t dst = ((((size_t)(seg * 7 + kc) * 2 + kh) * 25 + (co >> 4)) * 4 + qd) * 128
                         + (size_t)(co & 15) * 8;
        *(half8*)(Btf + dst) = v;
      }
    }
  }
}

// ---------------------------------------------------------------------------
// A-panel staging (4 waves): 130 halo pixels of row fy, k-chunk cb, into
// As[136][64] with XOR swizzle (row r's logical 16B-group g at phys g^(r&7)).
// ---------------------------------------------------------------------------
__device__ __forceinline__ void stage_a(const _Float16* __restrict__ Fh,
                                        int fy, int cb, _Float16* As, int t) {
  const int L = t & 63, w = t >> 6;
  const int srow = L >> 3;
  const int kofs = ((L & 7) ^ srow) * 8;   // pre-swizzled source k-group
  const _Float16* gA = Fh + (size_t)fy * HPAD * CPAD + kofs + cb;
#pragma unroll
  for (int j = 0; j < 4; ++j) {
    const int r = w * 32 + j * 8;
    async_ld16(gA + (size_t)(r + srow) * CPAD, &As[r * BKK]);
  }
  if (w == 0) {
    const int rr = 128 + srow;
    const int rp = (rr <= 129) ? rr : 129;  // rows 130..135 never read
    async_ld16(gA + (size_t)rp * CPAD, &As[128 * BKK]);
  }
}

// ---------------------------------------------------------------------------
// Fat conv: block = 128M(image row ya, x 0..127) x 128N(col0..+127), one dy
// (ks). 4 waves 2x2, wave 64x64 = acc[4][4]. Per kc: stage A, vmcnt+barrier,
// then 3 dx substeps {8 B-frag global loads (L2-hit, coalesced) + 8 A ds_reads
// + 32 MFMA} with NO barriers, then barrier. 14 barriers total per block.
// ---------------------------------------------------------------------------
__device__ __forceinline__ void conv_fat(const _Float16* __restrict__ Fh,
                                         const _Float16* __restrict__ Btf,
                                         _Float16* __restrict__ OMp,
                                         _Float16* As,
                                         int ya, int col0, int ks, int t) {
  const int L = t & 63, w = t >> 6;
  const int fr = L & 15, quad = L >> 4;
  const int wm = (w >> 1) * 64, wn = (w & 1) * 64;
  const int cob0 = (col0 + wn) >> 4;
  const int fy = ya + ks;                 // halo row = out row + dy + 1, dy = ks-1

  floatx4 acc[4][4];
#pragma unroll
  for (int i = 0; i < 4; ++i)
#pragma unroll
    for (int j = 0; j < 4; ++j) {
      floatx4 z = {0.f, 0.f, 0.f, 0.f};
      acc[i][j] = z;
    }

#pragma unroll 1
  for (int kc = 0; kc < 7; ++kc) {
    stage_a(Fh, fy, kc * BKK, As, t);
    asm volatile("s_waitcnt vmcnt(0)" ::: "memory");
    __builtin_amdgcn_s_barrier();
    asm volatile("" ::: "memory");

#pragma unroll
    for (int dxs = 0; dxs < 3; ++dxs) {
      const _Float16* Bp = Btf + (size_t)(ks * 42 + dxs * 14 + kc * 2) * BKHS
                         + (size_t)cob0 * 512 + quad * 128 + fr * 8;
      half8 b0[4], b1[4], a0[4], a1[4];
#pragma unroll
      for (int nt = 0; nt < 4; ++nt) b0[nt] = *(const half8*)(Bp + nt * 512);
#pragma unroll
      for (int nt = 0; nt < 4; ++nt) b1[nt] = *(const half8*)(Bp + BKHS + nt * 512);
#pragma unroll
      for (int mt = 0; mt < 4; ++mt) {
        const int row = wm + mt * 16 + fr + dxs;
        const int rk = row & 7;
        a0[mt] = *(const half8*)(&As[row * BKK + ((quad ^ rk) * 8)]);
        a1[mt] = *(const half8*)(&As[row * BKK + (((4 + quad) ^ rk) * 8)]);
      }
#pragma unroll
      for (int mt = 0; mt < 4; ++mt)
#pragma unroll
        for (int nt = 0; nt < 4; ++nt)
          acc[mt][nt] = __builtin_amdgcn_mfma_f32_16x16x32_f16(a0[mt], b0[nt], acc[mt][nt], 0, 0, 0);
#pragma unroll
      for (int mt = 0; mt < 4; ++mt)
#pragma unroll
        for (int nt = 0; nt < 4; ++nt)
          acc[mt][nt] = __builtin_amdgcn_mfma_f32_16x16x32_f16(a1[mt], b1[nt], acc[mt][nt], 0, 0, 0);
    }
    __builtin_amdgcn_s_barrier();   // protect As before next kc staging
    asm volatile("" ::: "memory");
  }

  // epilogue: C/D mapping col=lane&15, row=(lane>>4)*4+reg
#pragma unroll
  for (int mt = 0; mt < 4; ++mt) {
    const int rbase = ya * 128 + wm + mt * 16 + quad * 4;
#pragma unroll
    for (int nt = 0; nt < 4; ++nt) {
      const int col = col0 + wn + nt * 16 + fr;
      if (col < CC) {
#pragma unroll
        for (int r = 0; r < 4; ++r)
          OMp[(size_t)(rbase + r) * CC + col] = (_Float16)acc[mt][nt][r];
      }
    }
  }
}

// ---------------------------------------------------------------------------
// Thin conv: 128M x 16N (cols 384..399, real 384..391), one dy (ks).
// 4 waves stacked in M (wave 32M x 16N, acc[2]). Same barrier structure.
// ---------------------------------------------------------------------------
__device__ __forceinline__ void conv_thin(const _Float16* __restrict__ Fh,
                                          const _Float16* __restrict__ Btf,
                                          _Float16* __restrict__ OMp,
                                          _Float16* As,
                                          int ya, int ks, int t) {
  const int L = t & 63, w = t >> 6;
  const int fr = L & 15, quad = L >> 4;
  const int wm = w * 32;
  const int fy = ya + ks;

  floatx4 acc[2];
#pragma unroll
  for (int i = 0; i < 2; ++i) {
    floatx4 z = {0.f, 0.f, 0.f, 0.f};
    acc[i] = z;
  }

#pragma unroll 1
  for (int kc = 0; kc < 7; ++kc) {
    stage_a(Fh, fy, kc * BKK, As, t);
    asm volatile("s_waitcnt vmcnt(0)" ::: "memory");
    __builtin_amdgcn_s_barrier();
    asm volatile("" ::: "memory");

#pragma unroll
    for (int dxs = 0; dxs < 3; ++dxs) {
      const _Float16* Bp = Btf + (size_t)(ks * 42 + dxs * 14 + kc * 2) * BKHS
                         + (size_t)24 * 512 + quad * 128 + fr * 8;
      const half8 b0 = *(const half8*)(Bp);
      const half8 b1 = *(const half8*)(Bp + BKHS);
      half8 a0[2], a1[2];
#pragma unroll
      for (int mt = 0; mt < 2; ++mt) {
        const int row = wm + mt * 16 + fr + dxs;
        const int rk = row & 7;
        a0[mt] = *(const half8*)(&As[row * BKK + ((quad ^ rk) * 8)]);
        a1[mt] = *(const half8*)(&As[row * BKK + (((4 + quad) ^ rk) * 8)]);
      }
#pragma unroll
      for (int mt = 0; mt < 2; ++mt)
        acc[mt] = __builtin_amdgcn_mfma_f32_16x16x32_f16(a0[mt], b0, acc[mt], 0, 0, 0);
#pragma unroll
      for (int mt = 0; mt < 2; ++mt)
        acc[mt] = __builtin_amdgcn_mfma_f32_16x16x32_f16(a1[mt], b1, acc[mt], 0, 0, 0);
    }
    __builtin_amdgcn_s_barrier();
    asm volatile("" ::: "memory");
  }

#pragma unroll
  for (int mt = 0; mt < 2; ++mt) {
    const int rbase = ya * 128 + wm + mt * 16 + quad * 4;
    const int col = 384 + fr;
    if (col < CC) {
#pragma unroll
      for (int r = 0; r < 4; ++r)
        OMp[(size_t)(rbase + r) * CC + col] = (_Float16)acc[mt][r];
    }
  }
}

// ---------------------------------------------------------------------------
// Conv job decode on XCD-swizzled id: 12 jobs per image row:
// rem 0..8: fat, ks=rem/3, col=(rem%3)*128 (col-triples adjacent -> share the
// same A row in L2). rem 9..11: thin, ks=rem-9. Partial map OMp = OM[ks].
// ---------------------------------------------------------------------------
__device__ __forceinline__ void conv_dispatch(const _Float16* __restrict__ Fh,
                                              const _Float16* __restrict__ Btf,
                                              _Float16* __restrict__ OM0,
                                              _Float16* __restrict__ OM1,
                                              _Float16* __restrict__ OM2,
                                              _Float16* As, int bid2, int t) {
  const int row = bid2 / 12;
  const int rem = bid2 - row * 12;
  const int ks  = (rem < 9) ? (rem / 3) : (rem - 9);
  _Float16* OMp = (ks == 0) ? OM0 : (ks == 1) ? OM1 : OM2;
  if (rem < 9)
    conv_fat(Fh, Btf, OMp, As, row, (rem - ks * 3) * 128, ks, t);
  else
    conv_thin(Fh, Btf, OMp, As, row, ks, t);
}

// ---------------------------------------------------------------------------
// Pool (R5-verified, 3 maps): 8 lanes per (roi,bin).
// ---------------------------------------------------------------------------
__device__ __forceinline__ void bilin_setup(float y, float x,
                                            int& iy0, int& iy1, int& ix0, int& ix1,
                                            float& w00, float& w01, float& w10, float& w11) {
  const float y0f = floorf(y), x0f = floorf(x);
  const float wy = y - y0f, wx = x - x0f;   // unclamped, matches reference
  const int a = (int)y0f, b = (int)x0f;
  iy0 = min(max(a, 0), HH - 1);
  iy1 = min(max(a + 1, 0), HH - 1);
  ix0 = min(max(b, 0), WW - 1);
  ix1 = min(max(b + 1, 0), WW - 1);
  w00 = (1.f - wy) * (1.f - wx);
  w01 = (1.f - wy) * wx;
  w10 = wy * (1.f - wx);
  w11 = wy * wx;
}

__device__ __forceinline__ void pool_item8(const _Float16* __restrict__ Fh,
                                           const float* __restrict__ R,
                                           const _Float16* __restrict__ OM0,
                                           const _Float16* __restrict__ OM1,
                                           const _Float16* __restrict__ OM2,
                                           float* __restrict__ out, int tid) {
  const int j  = tid & 7;          // lane role within (roi,bin)
  const int nb = tid >> 3;
  const int n  = nb / NBIN;
  const int b  = nb - n * NBIN;
  const int bi = b / PSK;
  const int bj = b - bi * PSK;

  const float rx1 = R[n * 5 + 1], ry1 = R[n * 5 + 2];
  const float rx2 = R[n * 5 + 3], ry2 = R[n * 5 + 4];
  const float x1 = rx1 * (1.f / 16.f);
  const float y1 = ry1 * (1.f / 16.f);
  const float x2 = (rx2 + 1.f) * (1.f / 16.f);
  const float y2 = (ry2 + 1.f) * (1.f / 16.f);
  const float bw = (x2 - x1) * (1.f / 7.f);
  const float bh = (y2 - y1) * (1.f / 7.f);
  const float cx = x1 + ((float)bj + 0.5f) * bw;
  const float cy = y1 + ((float)bi + 0.5f) * bh;
  const float sxs = (rx2 - rx1 + 1.f) * (LAMDA / 16.f);
  const float sys = (ry2 - ry1 + 1.f) * (LAMDA / 16.f);

  // ---- stage 1: lane = (corner j&3, map-group j>>2) ----
  int iy0, iy1, ix0, ix1;
  float w00, w01, w10, w11;
  bilin_setup(cy, cx, iy0, iy1, ix0, ix1, w00, w01, w10, w11);

  const int c = j & 3;
  const int cyi = (c >> 1) ? iy1 : iy0;
  const int cxi = (c & 1) ? ix1 : ix0;
  const float wq = (c == 0) ? w00 : (c == 1) ? w01 : (c == 2) ? w10 : w11;

  const _Float16* OMp = (j >> 2) ? OM1 : OM0;
  const size_t base = (size_t)(cyi * WW + cxi) * CC + (size_t)b * 8;
  const half8 hv = *(const half8*)(OMp + base);

  float o8[8];
#pragma unroll
  for (int i = 0; i < 8; ++i) o8[i] = (float)hv[i];
  if (j < 4) {
    const half8 h2 = *(const half8*)(OM2 + base);
#pragma unroll
    for (int i = 0; i < 8; ++i) o8[i] += (float)h2[i];
  }
#pragma unroll
  for (int i = 0; i < 8; ++i) o8[i] *= wq;
#pragma unroll
  for (int i = 0; i < 8; ++i) o8[i] += __shfl_xor(o8[i], 1);
#pragma unroll
  for (int i = 0; i < 8; ++i) o8[i] += __shfl_xor(o8[i], 2);
#pragma unroll
  for (int i = 0; i < 8; ++i) o8[i] += __shfl_xor(o8[i], 4);

  const int g = j & 3;
  const float sx = cx + o8[2 * g] * sxs;
  const float sy = cy + o8[2 * g + 1] * sys;

  // ---- stage 2: lane = (group g, y-half j>>2); two half2 loads ----
  int jy0, jy1, jx0, jx1;
  float u00, u01, u10, u11;
  bilin_setup(sy, sx, jy0, jy1, jx0, jx1, u00, u01, u10, u11);

  const int  yh = j >> 2;
  const int  jy = yh ? jy1 : jy0;
  const float ua = yh ? u10 : u00;   // weight at (jy, jx0)
  const float ub = yh ? u11 : u01;   // weight at (jy, jx1)

  const size_t c0 = (size_t)b * 8 + 2 * g;
  const half2v qa = *(const half2v*)(Fh + ((size_t)(jy + 1) * HPAD + (jx0 + 1)) * CPAD + c0);
  const half2v qb = *(const half2v*)(Fh + ((size_t)(jy + 1) * HPAD + (jx1 + 1)) * CPAD + c0);

  float v0 = ua * (float)qa[0] + ub * (float)qb[0];
  float v1 = ua * (float)qa[1] + ub * (float)qb[1];
  v0 += __shfl_xor(v0, 4);
  v1 += __shfl_xor(v1, 4);

  const float vout = yh ? v1 : v0;
  out[((size_t)n * 8 + 2 * g + yh) * NBIN + b] = vout;
}

// ---------------------------------------------------------------------------
// Cooperative mega: prep -> sync -> conv (14-barrier hybrid) -> sync -> pool.
// ONE launch for everything. LDS 17.4 KB -> 6 blocks/CU for the 1536 grid.
// ---------------------------------------------------------------------------
__global__ __launch_bounds__(NTHR, 6)
void mega_kernel(const float* __restrict__ F, const float* __restrict__ Wt,
                 const float* __restrict__ R,
                 _Float16* __restrict__ OM0, _Float16* __restrict__ OM1,
                 _Float16* __restrict__ OM2,
                 _Float16* __restrict__ Fh, _Float16* __restrict__ Btf,
                 float* __restrict__ out) {
  __shared__ __align__(16) char smem[2 * ATH];   // 17408 B: A panel / prep tile
  const int bid = blockIdx.x;
  const int t = threadIdx.x;
  cg::grid_group grid = cg::this_grid();

  prep_features(F, Fh, bid * NTHR + t, GSTRIDE);
  prep_weights(Wt, Btf, (float(*)[33])smem, bid, t, NTHR, NBLK);

  __threadfence();
  grid.sync();

  // XCD-bijective swizzle (1536 % 8 == 0): each XCD gets 16 consecutive rows.
  const int bid2 = (bid & 7) * (NBLK / 8) + (bid >> 3);
  conv_dispatch(Fh, Btf, OM0, OM1, OM2, (_Float16*)smem, bid2, t);

  __threadfence();
  grid.sync();

  for (int idx = bid * NTHR + t; idx < POOL8; idx += GSTRIDE)
    pool_item8(Fh, R, OM0, OM1, OM2, out, idx);
}

// ---------------------------------------------------------------------------
// Non-coop fallback (same device code, separate launches)
// ---------------------------------------------------------------------------
__global__ __launch_bounds__(256)
void prep_kernel_sa(const float* __restrict__ F, const float* __restrict__ Wt,
                    _Float16* __restrict__ Fh, _Float16* __restrict__ Btf) {
  __shared__ float tile[32][33];
  prep_features(F, Fh, blockIdx.x * 256 + threadIdx.x, gridDim.x * 256);
  prep_weights(Wt, Btf, tile, blockIdx.x, threadIdx.x, 256, gridDim.x);
}

__global__ __launch_bounds__(NTHR, 6)
void conv_kernel_sa(const _Float16* __restrict__ Fh, const _Float16* __restrict__ Btf,
                    _Float16* __restrict__ OM0, _Float16* __restrict__ OM1,
                    _Float16* __restrict__ OM2) {
  __shared__ __align__(16) char smem[2 * ATH];
  const int bid2 = (blockIdx.x & 7) * (NBLK / 8) + (blockIdx.x >> 3);
  conv_dispatch(Fh, Btf, OM0, OM1, OM2, (_Float16*)smem, bid2, threadIdx.x);
}

__global__ __launch_bounds__(256)
void pool_kernel_sa(const _Float16* __restrict__ Fh, const float* __restrict__ R,
                    const _Float16* __restrict__ OM0, const _Float16* __restrict__ OM1,
                    const _Float16* __restrict__ OM2, float* __restrict__ out) {
  pool_item8(Fh, R, OM0, OM1, OM2, out, blockIdx.x * 256 + threadIdx.x);
}

extern "C" void kernel_launch(void* const* d_in, const int* in_sizes, int n_in,
                              void* d_out, int out_size, void* d_ws, size_t ws_size,
                              hipStream_t stream) {
  const float* F  = (const float*)d_in[0];   // features [1,128,128,392] fp32
  const float* R  = (const float*)d_in[1];   // rois [2048,5] fp32
  const float* Wt = (const float*)d_in[2];   // conv_w [3,3,392,392] fp32
  float* out = (float*)d_out;                // [2048,8,7,7] fp32

  const size_t omBytes  = (size_t)NPIX * CC * sizeof(_Float16);            // 12.85 MB
  const size_t fhBytes  = (size_t)HPAD * HPAD * CPAD * sizeof(_Float16);   // 15.14 MB
  // Btf: 3.23 MB; total ~57.0 MB (R5-proven workspace size)

  _Float16* OM0 = (_Float16*)d_ws;
  _Float16* OM1 = OM0 + (size_t)NPIX * CC;
  _Float16* OM2 = OM1 + (size_t)NPIX * CC;
  _Float16* Fh  = (_Float16*)((char*)d_ws + 3 * omBytes);
  _Float16* Btf = (_Float16*)((char*)d_ws + 3 * omBytes + fhBytes);

  int maxBlk = 0;
  hipError_t qerr = hipOccupancyMaxActiveBlocksPerMultiprocessor(&maxBlk, mega_kernel, NTHR, 0);
  bool coopOk = (qerr == hipSuccess && maxBlk >= 6);

  if (coopOk) {
    void* args[] = {(void*)&F, (void*)&Wt, (void*)&R, (void*)&OM0, (void*)&OM1,
                    (void*)&OM2, (void*)&Fh, (void*)&Btf, (void*)&out};
    hipError_t err = hipLaunchCooperativeKernel((const void*)mega_kernel,
                                                dim3(NBLK), dim3(NTHR),
                                                args, 0, stream);
    if (err != hipSuccess) {
      (void)hipGetLastError();
      coopOk = false;
    }
  }
  if (!coopOk) {
    prep_kernel_sa<<<2048, 256, 0, stream>>>(F, Wt, Fh, Btf);
    conv_kernel_sa<<<NBLK, NTHR, 0, stream>>>(Fh, Btf, OM0, OM1, OM2);
    pool_kernel_sa<<<POOL8 / 256, 256, 0, stream>>>(Fh, R, OM0, OM1, OM2, out);
  }
}

// Round 7
// 275.729 us; speedup vs baseline: 1.3979x; 1.3979x over previous
//
#include <hip/hip_runtime.h>
#include <hip/hip_cooperative_groups.h>
#include <cstddef>
#include <cstdint>

namespace cg = cooperative_groups;

// Problem constants (match reference setup_inputs)
#define HH    128
#define WW    128
#define CC    392           // K*K*8 = 49*8
#define NPIX  (HH*WW)       // 16384
#define NROI  2048
#define PSK   7
#define NBIN  49
#define LAMDA 0.1f

// MFMA conv layout constants
#define CPAD      448       // input channels padded to 7*64
#define HPAD      130       // 128 + 1px zero halo each side
#define SEGSTRIDE (9*CPAD)  // 4032 elems per co row in Bth
#define BKK       64        // K-chunk per barrier

// mega geometry: 1280 blocks x 256 threads, 5 blocks/CU (32 KB LDS exactly)
#define NBLK    1280
#define NTHR    256
#define GSTRIDE (NBLK*NTHR)
#define FTOT    (HPAD*HPAD*(CPAD/8))    // 946400 feature half8-groups
#define WTILES  (9*14*13)               // 1638 weight 32x32 tiles
#define POOL8   (NROI*NBIN*8)           // 802816 = 3136*256 exactly

typedef _Float16 half8   __attribute__((ext_vector_type(8)));
typedef _Float16 half2v  __attribute__((ext_vector_type(2)));
typedef float    floatx4 __attribute__((ext_vector_type(4)));

// ---------------------------------------------------------------------------
// async global->LDS 16B (dest = wave-uniform base + lane*16)
// ---------------------------------------------------------------------------
__device__ __forceinline__ void async_ld16(const _Float16* g, _Float16* l) {
  __builtin_amdgcn_global_load_lds((const __attribute__((address_space(1))) void*)g,
                                   (__attribute__((address_space(3))) void*)l,
                                   16, 0, 0);
}

// ---------------------------------------------------------------------------
// Prep 1: features fp32 [128,128,392] -> f16 [130,130,448] halo+pad (grid-stride)
// ---------------------------------------------------------------------------
__device__ __forceinline__ void prep_features(const float* __restrict__ F,
                                              _Float16* __restrict__ Fh,
                                              int gtid, int stride) {
  for (int idx = gtid; idx < FTOT; idx += stride) {
    const int p   = idx / (CPAD / 8);
    const int cgi = idx - p * (CPAD / 8);
    const int c   = cgi * 8;
    const int py  = p / HPAD;
    const int px  = p - py * HPAD;
    half8 h;
#pragma unroll
    for (int i = 0; i < 8; ++i) h[i] = (_Float16)0.f;
    if (py >= 1 && py <= HH && px >= 1 && px <= WW && c < CC) {
      const float* src = F + ((size_t)(py - 1) * WW + (px - 1)) * CC + c;
      const float4 v0 = *(const float4*)src;
      const float4 v1 = *(const float4*)(src + 4);
      h[0] = (_Float16)v0.x; h[1] = (_Float16)v0.y;
      h[2] = (_Float16)v0.z; h[3] = (_Float16)v0.w;
      h[4] = (_Float16)v1.x; h[5] = (_Float16)v1.y;
      h[6] = (_Float16)v1.z; h[7] = (_Float16)v1.w;
    }
    *(half8*)(Fh + (size_t)p * CPAD + c) = h;
  }
}

// ---------------------------------------------------------------------------
// Prep 2: weights fp32 [9,392,392] (seg,ci,co) -> f16 Bth[co][seg][ci'] via
// 32x32 LDS tile transpose; co rows 0..415 (392.. zero), ci padded to 448.
// ---------------------------------------------------------------------------
__device__ __forceinline__ void prep_weights(const float* __restrict__ Wt,
                                             _Float16* __restrict__ Bth,
                                             float (*tile)[33],
                                             int bid, int t, int bdim, int nblocks) {
  for (int tl = bid; tl < WTILES; tl += nblocks) {
    const int seg = tl / (14 * 13);
    const int rem = tl - seg * (14 * 13);
    const int cit = rem / 13;         // ci tile 0..13
    const int cot = rem - cit * 13;   // co tile 0..12
    const int ci0 = cit * 32, co0 = cot * 32;
    __syncthreads();                  // protect tile reuse across iterations
    for (int idx = t; idx < 1024; idx += bdim) {
      const int lr = idx >> 5;        // local ci
      const int lc = idx & 31;        // local co (fast -> coalesced read)
      const int ci = ci0 + lr, co = co0 + lc;
      float v = 0.f;
      if (ci < CC && co < CC) v = Wt[((size_t)seg * CC + ci) * CC + co];
      tile[lr][lc] = v;
    }
    __syncthreads();
    for (int idx = t; idx < 1024; idx += bdim) {
      const int lr = idx >> 5;        // local co
      const int lc = idx & 31;        // local ci (fast -> coalesced write)
      Bth[(size_t)(co0 + lr) * SEGSTRIDE + seg * CPAD + ci0 + lc] = (_Float16)tile[lc][lr];
    }
  }
}

// ---------------------------------------------------------------------------
// Fat conv: 128M x 128N output, ONE dy (=ks), K-split over dy. 4 waves 2x2,
// wave 64x64 = 4x4 mfma x2 per substep. A panel = 128 rows (halo px 1..128;
// halo cols 0/129 are structurally ZERO and handled by per-lane select) ->
// A+B LDS = 32 KB exactly -> 5 blocks/CU. A staged once per kc (shared across
// the 3 dx substeps); B staged per substep. R0-swizzle throughout.
// ---------------------------------------------------------------------------
__device__ __forceinline__ void conv_fat(const _Float16* __restrict__ Fh,
                                         const _Float16* __restrict__ Bth,
                                         _Float16* __restrict__ OMp,
                                         _Float16* As, _Float16* Bs,
                                         int ya, int col0, int dyi, int t) {
  const int L = t & 63;
  const int w = t >> 6;

  const int srow = L >> 3;                 // 0..7 row within 8-row staging inst
  const int kofs = ((L & 7) ^ srow) * 8;   // pre-swizzled source k-group
  const int nbase = col0 + w * 32 + srow;  // B co row; inst j adds j*8
  const int fy = ya + dyi;                 // Fh halo row (dy = dyi-1)

  const int wm = (w >> 1) * 64;
  const int wn = (w & 1) * 64;
  const int fr = L & 15;
  const int quad = L >> 4;
  const int pg0 = (quad ^ (fr & 7)) * 8;
  const int pg1 = ((4 + quad) ^ (fr & 7)) * 8;

  floatx4 acc[4][4];
#pragma unroll
  for (int i = 0; i < 4; ++i)
#pragma unroll
    for (int j = 0; j < 4; ++j) {
      floatx4 z = {0.f, 0.f, 0.f, 0.f};
      acc[i][j] = z;
    }

#pragma unroll 1
  for (int kc = 0; kc < 7; ++kc) {
    const int cb = kc * BKK;
    // stage A: 128 LDS rows <- halo px 1..128 of row fy (16 insts)
    {
      const _Float16* gA = Fh + ((size_t)fy * HPAD + 1) * CPAD + kofs + cb;
#pragma unroll
      for (int j = 0; j < 4; ++j) {
        const int r = w * 32 + j * 8;
        async_ld16(gA + (size_t)(r + srow) * CPAD, &As[r * BKK]);
      }
    }
#pragma unroll
    for (int dxs = 0; dxs < 3; ++dxs) {
      const int seg = dyi * 3 + dxs;
      const _Float16* gB = Bth + (size_t)nbase * SEGSTRIDE + seg * CPAD + kofs + cb;
#pragma unroll
      for (int j = 0; j < 4; ++j)
        async_ld16(gB + (size_t)(j * 8) * SEGSTRIDE, &Bs[(w * 32 + j * 8) * BKK]);
      __syncthreads();   // drains vmcnt -> A panel (+B tile) ready

      half8 a0[4], a1[4], b0[4], b1[4];
#pragma unroll
      for (int mt = 0; mt < 4; ++mt) {
        int row = wm + mt * 16 + fr + dxs - 1;   // LDS row = halo px - 1
        bool oob = false;
        if (dxs == 0 && mt == 0) { oob = (row < 0);   if (oob) row = 0; }
        if (dxs == 2 && mt == 3) { oob = (row > 127); if (oob) row = 127; }
        const int rk = row & 7;
        a0[mt] = *(const half8*)(&As[row * BKK + ((quad ^ rk) * 8)]);
        a1[mt] = *(const half8*)(&As[row * BKK + (((4 + quad) ^ rk) * 8)]);
        if ((dxs == 0 && mt == 0) || (dxs == 2 && mt == 3)) {
          if (oob) {     // halo column: contribution is zero
#pragma unroll
            for (int e = 0; e < 8; ++e) { a0[mt][e] = (_Float16)0.f; a1[mt][e] = (_Float16)0.f; }
          }
        }
      }
#pragma unroll
      for (int nt = 0; nt < 4; ++nt) {
        const int rb = (wn + nt * 16 + fr) * BKK;
        b0[nt] = *(const half8*)(&Bs[rb + pg0]);
        b1[nt] = *(const half8*)(&Bs[rb + pg1]);
      }
#pragma unroll
      for (int mt = 0; mt < 4; ++mt)
#pragma unroll
        for (int nt = 0; nt < 4; ++nt)
          acc[mt][nt] = __builtin_amdgcn_mfma_f32_16x16x32_f16(a0[mt], b0[nt], acc[mt][nt], 0, 0, 0);
#pragma unroll
      for (int mt = 0; mt < 4; ++mt)
#pragma unroll
        for (int nt = 0; nt < 4; ++nt)
          acc[mt][nt] = __builtin_amdgcn_mfma_f32_16x16x32_f16(a1[mt], b1[nt], acc[mt][nt], 0, 0, 0);
      __syncthreads();   // protect LDS before next staging
    }
  }

  // epilogue: C/D mapping col=lane&15, row=(lane>>4)*4+reg
#pragma unroll
  for (int mt = 0; mt < 4; ++mt) {
    const int rbase = ya * 128 + wm + mt * 16 + quad * 4;
#pragma unroll
    for (int nt = 0; nt < 4; ++nt) {
      const int col = col0 + wn + nt * 16 + fr;
      if (col < CC) {
#pragma unroll
        for (int r = 0; r < 4; ++r)
          OMp[(size_t)(rbase + r) * CC + col] = (_Float16)acc[mt][nt][r];
      }
    }
  }
}

// ---------------------------------------------------------------------------
// Thin conv (cols 384..391), FULL K, barrier-free direct-global: B slice is
// 129 KB (L2-resident), A frags read straight from Fh (halo present). 4 waves
// stacked in M (wave 32M x 16N, acc[2]). Writes sum to OM0 and ZEROS to
// OM1/OM2 so the 3-map pool needs no special case for bin 48.
// ---------------------------------------------------------------------------
__device__ __forceinline__ void conv_thin(const _Float16* __restrict__ Fh,
                                          const _Float16* __restrict__ Bth,
                                          _Float16* __restrict__ OM0,
                                          _Float16* __restrict__ OM1,
                                          _Float16* __restrict__ OM2,
                                          int ya, int t) {
  const int L = t & 63, w = t >> 6;
  const int fr = L & 15, quad = L >> 4;
  const int wm = w * 32;

  floatx4 acc[2];
#pragma unroll
  for (int i = 0; i < 2; ++i) {
    floatx4 z = {0.f, 0.f, 0.f, 0.f};
    acc[i] = z;
  }

#pragma unroll 1
  for (int dyi = 0; dyi < 3; ++dyi) {
    const int fy = ya + dyi;
#pragma unroll 1
    for (int kc = 0; kc < 7; ++kc) {
#pragma unroll
      for (int dxs = 0; dxs < 3; ++dxs) {
        const int seg = dyi * 3 + dxs;
        const _Float16* bb = Bth + (size_t)(384 + fr) * SEGSTRIDE + seg * CPAD + kc * 64 + quad * 8;
        const _Float16* ab = Fh + ((size_t)fy * HPAD + wm + dxs) * CPAD + kc * 64 + quad * 8;
#pragma unroll
        for (int kh = 0; kh < 2; ++kh) {
          const half8 b = *(const half8*)(bb + kh * 32);
          half8 a[2];
#pragma unroll
          for (int mt = 0; mt < 2; ++mt)
            a[mt] = *(const half8*)(ab + (size_t)(mt * 16 + fr) * CPAD + kh * 32);
#pragma unroll
          for (int mt = 0; mt < 2; ++mt)
            acc[mt] = __builtin_amdgcn_mfma_f32_16x16x32_f16(a[mt], b, acc[mt], 0, 0, 0);
        }
      }
    }
  }

#pragma unroll
  for (int mt = 0; mt < 2; ++mt) {
    const int rbase = ya * 128 + wm + mt * 16 + quad * 4;
    const int col = 384 + fr;
    if (col < CC) {
#pragma unroll
      for (int r = 0; r < 4; ++r) {
        const size_t o = (size_t)(rbase + r) * CC + col;
        OM0[o] = (_Float16)acc[mt][r];
        OM1[o] = (_Float16)0.f;
        OM2[o] = (_Float16)0.f;
      }
    }
  }
}

// ---------------------------------------------------------------------------
// Conv job decode on XCD-swizzled bid2: row = bid2/10, j = bid2%10.
// j<9: fat, col=(j%3)*128, ks=j/3 (=dy index, K-split) -> OM[ks].
// j==9: thin full-K direct-global.
// ---------------------------------------------------------------------------
__device__ __forceinline__ void conv_dispatch(const _Float16* __restrict__ Fh,
                                              const _Float16* __restrict__ Bth,
                                              _Float16* __restrict__ OM0,
                                              _Float16* __restrict__ OM1,
                                              _Float16* __restrict__ OM2,
                                              _Float16* As, _Float16* Bs,
                                              int bid2, int t) {
  const int row = bid2 / 10;
  const int j   = bid2 - row * 10;
  if (j < 9) {
    const int ks = j / 3;
    _Float16* OMp = (ks == 0) ? OM0 : (ks == 1) ? OM1 : OM2;
    conv_fat(Fh, Bth, OMp, As, Bs, row, (j - ks * 3) * 128, ks, t);
  } else {
    conv_thin(Fh, Bth, OM0, OM1, OM2, row, t);
  }
}

// ---------------------------------------------------------------------------
// Pool (R5-verified, 3 maps): 8 lanes per (roi,bin).
// ---------------------------------------------------------------------------
__device__ __forceinline__ void bilin_setup(float y, float x,
                                            int& iy0, int& iy1, int& ix0, int& ix1,
                                            float& w00, float& w01, float& w10, float& w11) {
  const float y0f = floorf(y), x0f = floorf(x);
  const float wy = y - y0f, wx = x - x0f;   // unclamped, matches reference
  const int a = (int)y0f, b = (int)x0f;
  iy0 = min(max(a, 0), HH - 1);
  iy1 = min(max(a + 1, 0), HH - 1);
  ix0 = min(max(b, 0), WW - 1);
  ix1 = min(max(b + 1, 0), WW - 1);
  w00 = (1.f - wy) * (1.f - wx);
  w01 = (1.f - wy) * wx;
  w10 = wy * (1.f - wx);
  w11 = wy * wx;
}

__device__ __forceinline__ void pool_item8(const _Float16* __restrict__ Fh,
                                           const float* __restrict__ R,
                                           const _Float16* __restrict__ OM0,
                                           const _Float16* __restrict__ OM1,
                                           const _Float16* __restrict__ OM2,
                                           float* __restrict__ out, int tid) {
  const int j  = tid & 7;          // lane role within (roi,bin)
  const int nb = tid >> 3;
  const int n  = nb / NBIN;
  const int b  = nb - n * NBIN;
  const int bi = b / PSK;
  const int bj = b - bi * PSK;

  const float rx1 = R[n * 5 + 1], ry1 = R[n * 5 + 2];
  const float rx2 = R[n * 5 + 3], ry2 = R[n * 5 + 4];
  const float x1 = rx1 * (1.f / 16.f);
  const float y1 = ry1 * (1.f / 16.f);
  const float x2 = (rx2 + 1.f) * (1.f / 16.f);
  const float y2 = (ry2 + 1.f) * (1.f / 16.f);
  const float bw = (x2 - x1) * (1.f / 7.f);
  const float bh = (y2 - y1) * (1.f / 7.f);
  const float cx = x1 + ((float)bj + 0.5f) * bw;
  const float cy = y1 + ((float)bi + 0.5f) * bh;
  const float sxs = (rx2 - rx1 + 1.f) * (LAMDA / 16.f);
  const float sys = (ry2 - ry1 + 1.f) * (LAMDA / 16.f);

  // ---- stage 1: lane = (corner j&3, map-group j>>2) ----
  int iy0, iy1, ix0, ix1;
  float w00, w01, w10, w11;
  bilin_setup(cy, cx, iy0, iy1, ix0, ix1, w00, w01, w10, w11);

  const int c = j & 3;
  const int cyi = (c >> 1) ? iy1 : iy0;
  const int cxi = (c & 1) ? ix1 : ix0;
  const float wq = (c == 0) ? w00 : (c == 1) ? w01 : (c == 2) ? w10 : w11;

  const _Float16* OMp = (j >> 2) ? OM1 : OM0;
  const size_t base = (size_t)(cyi * WW + cxi) * CC + (size_t)b * 8;
  const half8 hv = *(const half8*)(OMp + base);

  float o8[8];
#pragma unroll
  for (int i = 0; i < 8; ++i) o8[i] = (float)hv[i];
  if (j < 4) {
    const half8 h2 = *(const half8*)(OM2 + base);
#pragma unroll
    for (int i = 0; i < 8; ++i) o8[i] += (float)h2[i];
  }
#pragma unroll
  for (int i = 0; i < 8; ++i) o8[i] *= wq;
#pragma unroll
  for (int i = 0; i < 8; ++i) o8[i] += __shfl_xor(o8[i], 1);
#pragma unroll
  for (int i = 0; i < 8; ++i) o8[i] += __shfl_xor(o8[i], 2);
#pragma unroll
  for (int i = 0; i < 8; ++i) o8[i] += __shfl_xor(o8[i], 4);

  const int g = j & 3;
  const float sx = cx + o8[2 * g] * sxs;
  const float sy = cy + o8[2 * g + 1] * sys;

  // ---- stage 2: lane = (group g, y-half j>>2); two half2 loads ----
  int jy0, jy1, jx0, jx1;
  float u00, u01, u10, u11;
  bilin_setup(sy, sx, jy0, jy1, jx0, jx1, u00, u01, u10, u11);

  const int  yh = j >> 2;
  const int  jy = yh ? jy1 : jy0;
  const float ua = yh ? u10 : u00;   // weight at (jy, jx0)
  const float ub = yh ? u11 : u01;   // weight at (jy, jx1)

  const size_t c0 = (size_t)b * 8 + 2 * g;
  const half2v qa = *(const half2v*)(Fh + ((size_t)(jy + 1) * HPAD + (jx0 + 1)) * CPAD + c0);
  const half2v qb = *(const half2v*)(Fh + ((size_t)(jy + 1) * HPAD + (jx1 + 1)) * CPAD + c0);

  float v0 = ua * (float)qa[0] + ub * (float)qb[0];
  float v1 = ua * (float)qa[1] + ub * (float)qb[1];
  v0 += __shfl_xor(v0, 4);
  v1 += __shfl_xor(v1, 4);

  const float vout = yh ? v1 : v0;
  out[((size_t)n * 8 + 2 * g + yh) * NBIN + b] = vout;
}

// ---------------------------------------------------------------------------
// Cooperative mega: prep -> grid.sync -> conv. 1280 blocks x 256 threads,
// LDS 32 KB exactly -> 5 blocks/CU (20 waves/CU). Pool stays separate.
// ---------------------------------------------------------------------------
__global__ __launch_bounds__(NTHR, 5)
void mega_kernel(const float* __restrict__ F, const float* __restrict__ Wt,
                 _Float16* __restrict__ OM0, _Float16* __restrict__ OM1,
                 _Float16* __restrict__ OM2,
                 _Float16* __restrict__ Fh, _Float16* __restrict__ Bth) {
  __shared__ __align__(16) _Float16 smem[2 * 128 * BKK];  // 32768 B exactly
  const int bid = blockIdx.x;
  const int t = threadIdx.x;
  cg::grid_group grid = cg::this_grid();

  prep_features(F, Fh, bid * NTHR + t, GSTRIDE);
  prep_weights(Wt, Bth, (float(*)[33])smem, bid, t, NTHR, NBLK);

  __threadfence();
  grid.sync();

  // XCD-bijective swizzle (1280/8 = 160): XCD k gets rows 16k..16k+15.
  const int bid2 = (bid & 7) * (NBLK / 8) + (bid >> 3);
  conv_dispatch(Fh, Bth, OM0, OM1, OM2, smem, smem + 128 * BKK, bid2, t);
}

__global__ __launch_bounds__(256)
void pool_kernel(const _Float16* __restrict__ Fh, const float* __restrict__ R,
                 const _Float16* __restrict__ OM0, const _Float16* __restrict__ OM1,
                 const _Float16* __restrict__ OM2, float* __restrict__ out) {
  pool_item8(Fh, R, OM0, OM1, OM2, out, blockIdx.x * 256 + threadIdx.x);
}

// ---------------------------------------------------------------------------
// Non-coop fallback (same device code, separate launches)
// ---------------------------------------------------------------------------
__global__ __launch_bounds__(256)
void prep_kernel_sa(const float* __restrict__ F, const float* __restrict__ Wt,
                    _Float16* __restrict__ Fh, _Float16* __restrict__ Bth) {
  __shared__ float tile[32][33];
  prep_features(F, Fh, blockIdx.x * 256 + threadIdx.x, gridDim.x * 256);
  prep_weights(Wt, Bth, tile, blockIdx.x, threadIdx.x, 256, gridDim.x);
}

__global__ __launch_bounds__(NTHR, 5)
void conv_kernel_sa(const _Float16* __restrict__ Fh, const _Float16* __restrict__ Bth,
                    _Float16* __restrict__ OM0, _Float16* __restrict__ OM1,
                    _Float16* __restrict__ OM2) {
  __shared__ __align__(16) _Float16 smem[2 * 128 * BKK];
  const int bid2 = (blockIdx.x & 7) * (NBLK / 8) + (blockIdx.x >> 3);
  conv_dispatch(Fh, Bth, OM0, OM1, OM2, smem, smem + 128 * BKK, bid2, threadIdx.x);
}

extern "C" void kernel_launch(void* const* d_in, const int* in_sizes, int n_in,
                              void* d_out, int out_size, void* d_ws, size_t ws_size,
                              hipStream_t stream) {
  const float* F  = (const float*)d_in[0];   // features [1,128,128,392] fp32
  const float* R  = (const float*)d_in[1];   // rois [2048,5] fp32
  const float* Wt = (const float*)d_in[2];   // conv_w [3,3,392,392] fp32
  float* out = (float*)d_out;                // [2048,8,7,7] fp32

  const size_t omBytes  = (size_t)NPIX * CC * sizeof(_Float16);            // 12.85 MB
  const size_t fhBytes  = (size_t)HPAD * HPAD * CPAD * sizeof(_Float16);   // 15.14 MB
  // Bth: 416 * 4032 * 2B = 3.35 MB; total ~57.0 MB

  _Float16* OM0 = (_Float16*)d_ws;
  _Float16* OM1 = OM0 + (size_t)NPIX * CC;
  _Float16* OM2 = OM1 + (size_t)NPIX * CC;
  _Float16* Fh  = (_Float16*)((char*)d_ws + 3 * omBytes);
  _Float16* Bth = (_Float16*)((char*)d_ws + 3 * omBytes + fhBytes);

  int maxBlk = 0;
  hipError_t qerr = hipOccupancyMaxActiveBlocksPerMultiprocessor(&maxBlk, mega_kernel, NTHR, 0);
  bool coopOk = (qerr == hipSuccess && maxBlk >= 5);

  if (coopOk) {
    void* args[] = {(void*)&F, (void*)&Wt, (void*)&OM0, (void*)&OM1, (void*)&OM2,
                    (void*)&Fh, (void*)&Bth};
    hipError_t err = hipLaunchCooperativeKernel((const void*)mega_kernel,
                                                dim3(NBLK), dim3(NTHR),
                                                args, 0, stream);
    if (err != hipSuccess) {
      (void)hipGetLastError();
      coopOk = false;
    }
  }
  if (!coopOk) {
    prep_kernel_sa<<<2048, 256, 0, stream>>>(F, Wt, Fh, Bth);
    conv_kernel_sa<<<NBLK, NTHR, 0, stream>>>(Fh, Bth, OM0, OM1, OM2);
  }

  pool_kernel<<<POOL8 / 256, 256, 0, stream>>>(Fh, R, OM0, OM1, OM2, out);
}

// Round 8
// 150.218 us; speedup vs baseline: 2.5658x; 1.8355x over previous
//
#include <hip/hip_runtime.h>
#include <hip/hip_cooperative_groups.h>
#include <cstddef>
#include <cstdint>

namespace cg = cooperative_groups;

// Problem constants (match reference setup_inputs)
#define HH    128
#define WW    128
#define CC    392           // K*K*8 = 49*8
#define NPIX  (HH*WW)       // 16384
#define NROI  2048
#define PSK   7
#define NBIN  49
#define LAMDA 0.1f

// MFMA conv layout constants
#define CPAD      448       // input channels padded to 7*64
#define HPAD      130       // 128 + 1px zero halo each side
#define SEGSTRIDE (9*CPAD)  // 4032 elems per co row in Bth
#define BKK       64        // K-chunk per barrier
#define NSS       21        // supersteps: 3 dy x 7 k-chunks
#define SSPLIT    10        // split-K boundary (ss 0..9 -> OMa, 10..20 -> OMb)

// LDS: A panel 136 rows (130 used) x 64 halves, B tile 128 x 64 halves
#define AROWS   136
#define ATH     (AROWS*BKK)   // 8704 halves = 17408 B
#define BTH     (128*BKK)     // 8192 halves = 16384 B

// mega-kernel geometry
#define NBLK    1024
#define NTHR    256
#define GSTRIDE (NBLK*NTHR)
#define FTOT    (HPAD*HPAD*(CPAD/8))    // 946400 feature half8-groups
#define WTILES  (9*14*13)               // 1638 weight 32x32 tiles
#define POOL8   (NROI*NBIN*8)           // 802816 = 3136*256 exactly

typedef _Float16 half8   __attribute__((ext_vector_type(8)));
typedef _Float16 half2v  __attribute__((ext_vector_type(2)));
typedef float    floatx4 __attribute__((ext_vector_type(4)));

// ---------------------------------------------------------------------------
// async global->LDS 16B (dest = wave-uniform base + lane*16)
// ---------------------------------------------------------------------------
__device__ __forceinline__ void async_ld16(const _Float16* g, _Float16* l) {
  __builtin_amdgcn_global_load_lds((const __attribute__((address_space(1))) void*)g,
                                   (__attribute__((address_space(3))) void*)l,
                                   16, 0, 0);
}

// ---------------------------------------------------------------------------
// Prep 1: features fp32 [128,128,392] -> f16 [130,130,448] halo+pad (grid-stride)
// ---------------------------------------------------------------------------
__device__ __forceinline__ void prep_features(const float* __restrict__ F,
                                              _Float16* __restrict__ Fh,
                                              int gtid, int stride) {
  for (int idx = gtid; idx < FTOT; idx += stride) {
    const int p   = idx / (CPAD / 8);
    const int cgi = idx - p * (CPAD / 8);
    const int c   = cgi * 8;
    const int py  = p / HPAD;
    const int px  = p - py * HPAD;
    half8 h;
#pragma unroll
    for (int i = 0; i < 8; ++i) h[i] = (_Float16)0.f;
    if (py >= 1 && py <= HH && px >= 1 && px <= WW && c < CC) {
      const float* src = F + ((size_t)(py - 1) * WW + (px - 1)) * CC + c;
      const float4 v0 = *(const float4*)src;
      const float4 v1 = *(const float4*)(src + 4);
      h[0] = (_Float16)v0.x; h[1] = (_Float16)v0.y;
      h[2] = (_Float16)v0.z; h[3] = (_Float16)v0.w;
      h[4] = (_Float16)v1.x; h[5] = (_Float16)v1.y;
      h[6] = (_Float16)v1.z; h[7] = (_Float16)v1.w;
    }
    *(half8*)(Fh + (size_t)p * CPAD + c) = h;
  }
}

// ---------------------------------------------------------------------------
// Prep 2: weights fp32 [9,392,392] (seg,ci,co) -> f16 Bth[co][seg][ci'] via
// 32x32 LDS tile transpose; co rows 0..415 (392.. zero), ci padded to 448.
// ---------------------------------------------------------------------------
__device__ __forceinline__ void prep_weights(const float* __restrict__ Wt,
                                             _Float16* __restrict__ Bth,
                                             float (*tile)[33],
                                             int bid, int t, int nblocks) {
  for (int tl = bid; tl < WTILES; tl += nblocks) {
    const int seg = tl / (14 * 13);
    const int rem = tl - seg * (14 * 13);
    const int cit = rem / 13;         // ci tile 0..13
    const int cot = rem - cit * 13;   // co tile 0..12
    const int ci0 = cit * 32, co0 = cot * 32;
    __syncthreads();                  // protect tile reuse across iterations
#pragma unroll
    for (int i = 0; i < 4; ++i) {
      const int idx = t + i * 256;
      const int lr = idx >> 5;        // local ci
      const int lc = idx & 31;        // local co (fast -> coalesced read)
      const int ci = ci0 + lr, co = co0 + lc;
      float v = 0.f;
      if (ci < CC && co < CC) v = Wt[((size_t)seg * CC + ci) * CC + co];
      tile[lr][lc] = v;
    }
    __syncthreads();
#pragma unroll
    for (int i = 0; i < 4; ++i) {
      const int idx = t + i * 256;
      const int lr = idx >> 5;        // local co
      const int lc = idx & 31;        // local ci (fast -> coalesced write)
      Bth[(size_t)(co0 + lr) * SEGSTRIDE + seg * CPAD + ci0 + lc] = (_Float16)tile[lc][lr];
    }
  }
}

// ---------------------------------------------------------------------------
// A-panel staging: 130 Fh pixels (x0-1..x0+128 in image coords == Fh px 0..129)
// of row fy, k-chunk cb, into As[136][64] with the XOR swizzle (row r's
// logical 16B-group g stored at phys g^(r&7)). Waves 0-3 stage rows 0..127;
// wave 0 stages the tail inst rows 128..135 (sources clamped to px 129).
// ---------------------------------------------------------------------------
__device__ __forceinline__ void stage_a130(const _Float16* __restrict__ Fh,
                                           int fy, int cb, _Float16* As, int t) {
  const int L = t & 63, w = t >> 6;
  const int srow = L >> 3;                 // row-within-8 of each inst
  const int kofs = ((L & 7) ^ srow) * 8;   // pre-swizzled source k-group
  const _Float16* gA = Fh + (size_t)fy * HPAD * CPAD + kofs + cb;
#pragma unroll
  for (int j = 0; j < 4; ++j) {
    const int r = w * 32 + j * 8 + srow;
    async_ld16(gA + (size_t)r * CPAD, &As[(w * 32 + j * 8) * BKK]);
  }
  if (w == 0) {
    const int r = 128 + srow;
    const int rp = (r <= 129) ? r : 129;   // clamp: rows 130..135 never read
    async_ld16(gA + (size_t)rp * CPAD, &As[128 * BKK]);
  }
}

// ---------------------------------------------------------------------------
// Fat conv tile: 128M x 128N output, BK=64, 4 waves 2x2, wave 64x64 =
// 4x4 mfma_f32_16x16x32_f16 x2 per barrier-step. Superstep = (dy, k-chunk):
// A panel (130 px) staged ONCE, then 3 dx sub-steps re-stage only B (16 KB)
// and read A at row offset +dxs. Cuts A staging traffic 3x vs per-seg.
// ---------------------------------------------------------------------------
__device__ __forceinline__ void conv_fat(const _Float16* __restrict__ Fh,
                                         const _Float16* __restrict__ Bth,
                                         _Float16* __restrict__ OMp,
                                         _Float16* As, _Float16* Bs,
                                         int row0, int col0, int s0, int s1, int t) {
  const int L = t & 63;
  const int w = t >> 6;

  const int srow = L >> 3;
  const int kofs = ((L & 7) ^ srow) * 8;
  const int ya = row0 >> 7;                // image y for this M-tile
  const int nbase = col0 + w * 32 + srow;  // B co row; inst j adds j*8

  const int wm = (w >> 1) * 64;
  const int wn = (w & 1) * 64;
  const int fr = L & 15;
  const int quad = L >> 4;

  floatx4 acc[4][4];
#pragma unroll
  for (int i = 0; i < 4; ++i)
#pragma unroll
    for (int j = 0; j < 4; ++j) {
      floatx4 z = {0.f, 0.f, 0.f, 0.f};
      acc[i][j] = z;
    }

  for (int s = s0; s < s1; ++s) {
    const int dyi = s / 7;                 // 0..2  (dy = dyi-1)
    const int it  = s - dyi * 7;
    const int fy  = ya + dyi;              // Fh row (halo coords)
    const int cb  = it * BKK;

    stage_a130(Fh, fy, cb, As, t);         // once per superstep

    for (int dxs = 0; dxs < 3; ++dxs) {    // dx = dxs-1
      const int seg = dyi * 3 + dxs;
      const _Float16* gB = Bth + (size_t)nbase * SEGSTRIDE + seg * CPAD + kofs + cb;
#pragma unroll
      for (int j = 0; j < 4; ++j)
        async_ld16(gB + (size_t)(j * 8) * SEGSTRIDE, &Bs[(w * 32 + j * 8) * BKK]);
      __syncthreads();   // drains vmcnt -> A panel + B tile ready

      half8 a0[4], a1[4], b0[4], b1[4];
#pragma unroll
      for (int mt = 0; mt < 4; ++mt) {
        const int row = wm + mt * 16 + fr + dxs;   // A row = out pixel + dx + 1
        const int rk = row & 7;
        a0[mt] = *(const half8*)(&As[row * BKK + ((quad ^ rk) * 8)]);
        a1[mt] = *(const half8*)(&As[row * BKK + (((4 + quad) ^ rk) * 8)]);
      }
#pragma unroll
      for (int nt = 0; nt < 4; ++nt) {
        const int rb = (wn + nt * 16 + fr) * BKK;
        const int rk = fr & 7;
        b0[nt] = *(const half8*)(&Bs[rb + ((quad ^ rk) * 8)]);
        b1[nt] = *(const half8*)(&Bs[rb + (((4 + quad) ^ rk) * 8)]);
      }
#pragma unroll
      for (int mt = 0; mt < 4; ++mt)
#pragma unroll
        for (int nt = 0; nt < 4; ++nt)
          acc[mt][nt] = __builtin_amdgcn_mfma_f32_16x16x32_f16(a0[mt], b0[nt], acc[mt][nt], 0, 0, 0);
#pragma unroll
      for (int mt = 0; mt < 4; ++mt)
#pragma unroll
        for (int nt = 0; nt < 4; ++nt)
          acc[mt][nt] = __builtin_amdgcn_mfma_f32_16x16x32_f16(a1[mt], b1[nt], acc[mt][nt], 0, 0, 0);
      __syncthreads();   // protect LDS before next staging
    }
  }

  // epilogue: C/D mapping col=lane&15, row=(lane>>4)*4+reg; f16 partial store
#pragma unroll
  for (int mt = 0; mt < 4; ++mt) {
    const int rbase = row0 + wm + mt * 16 + quad * 4;
#pragma unroll
    for (int nt = 0; nt < 4; ++nt) {
      const int col = col0 + wn + nt * 16 + fr;
      if (col < CC) {
#pragma unroll
        for (int r = 0; r < 4; ++r)
          OMp[(size_t)(rbase + r) * CC + col] = (_Float16)acc[mt][nt][r];
      }
    }
  }
}

// ---------------------------------------------------------------------------
// Thin conv tile: 128M x 16N (cols 384..399, real 384..391).
// 4 waves stacked in M (wave 32M x 16N, acc 2x1). Waves 0-1 stage B rows.
// Same superstep A-panel sharing as conv_fat.
// ---------------------------------------------------------------------------
__device__ __forceinline__ void conv_thin(const _Float16* __restrict__ Fh,
                                          const _Float16* __restrict__ Bth,
                                          _Float16* __restrict__ OMp,
                                          _Float16* As, _Float16* Bs,
                                          int row0, int s0, int s1, int t) {
  const int L = t & 63;
  const int w = t >> 6;

  const int srow = L >> 3;
  const int kofs = ((L & 7) ^ srow) * 8;
  const int ya = row0 >> 7;
  const int nbase = 384 + w * 8 + srow;    // valid when w < 2

  const int wm = w * 32;
  const int fr = L & 15;
  const int quad = L >> 4;

  floatx4 acc[2];
#pragma unroll
  for (int i = 0; i < 2; ++i) {
    floatx4 z = {0.f, 0.f, 0.f, 0.f};
    acc[i] = z;
  }

  for (int s = s0; s < s1; ++s) {
    const int dyi = s / 7;
    const int it  = s - dyi * 7;
    const int fy  = ya + dyi;
    const int cb  = it * BKK;

    stage_a130(Fh, fy, cb, As, t);

    for (int dxs = 0; dxs < 3; ++dxs) {
      const int seg = dyi * 3 + dxs;
      if (w < 2) {
        const _Float16* gB = Bth + (size_t)nbase * SEGSTRIDE + seg * CPAD + kofs + cb;
        async_ld16(gB, &Bs[(w * 8) * BKK]);
      }
      __syncthreads();

      half8 a0[2], a1[2];
#pragma unroll
      for (int mt = 0; mt < 2; ++mt) {
        const int row = wm + mt * 16 + fr + dxs;
        const int rk = row & 7;
        a0[mt] = *(const half8*)(&As[row * BKK + ((quad ^ rk) * 8)]);
        a1[mt] = *(const half8*)(&As[row * BKK + (((4 + quad) ^ rk) * 8)]);
      }
      const int rk = fr & 7;
      const half8 b0 = *(const half8*)(&Bs[fr * BKK + ((quad ^ rk) * 8)]);
      const half8 b1 = *(const half8*)(&Bs[fr * BKK + (((4 + quad) ^ rk) * 8)]);
#pragma unroll
      for (int mt = 0; mt < 2; ++mt)
        acc[mt] = __builtin_amdgcn_mfma_f32_16x16x32_f16(a0[mt], b0, acc[mt], 0, 0, 0);
#pragma unroll
      for (int mt = 0; mt < 2; ++mt)
        acc[mt] = __builtin_amdgcn_mfma_f32_16x16x32_f16(a1[mt], b1, acc[mt], 0, 0, 0);
      __syncthreads();
    }
  }

#pragma unroll
  for (int mt = 0; mt < 2; ++mt) {
    const int rbase = row0 + wm + mt * 16 + quad * 4;
    const int col = 384 + fr;
    if (col < CC) {
#pragma unroll
      for (int r = 0; r < 4; ++r)
        OMp[(size_t)(rbase + r) * CC + col] = (_Float16)acc[mt][r];
    }
  }
}

// ---------------------------------------------------------------------------
// Conv block decode: bid in [0,1024). x = bid&127 (M-block), rest = bid>>7:
// rest 0..5 -> fat col {0,1,2}, kz = rest/3. rest 6,7 -> thin, kz = rest-6.
// kz selects superstep range [0,SSPLIT) -> OMa, [SSPLIT,NSS) -> OMb.
// ---------------------------------------------------------------------------
__device__ __forceinline__ void conv_dispatch(const _Float16* Fh, const _Float16* Bth,
                                              _Float16* OMa, _Float16* OMb,
                                              _Float16* As, _Float16* Bs,
                                              int bid, int t) {
  const int x = bid & 127;
  const int rest = bid >> 7;
  const int kz = (rest < 6) ? (rest / 3) : (rest - 6);
  _Float16* OMp = kz ? OMb : OMa;
  const int s0 = kz ? SSPLIT : 0;
  const int s1 = kz ? NSS : SSPLIT;
  if (rest < 6)
    conv_fat(Fh, Bth, OMp, As, Bs, x * 128, (rest % 3) * 128, s0, s1, t);
  else
    conv_thin(Fh, Bth, OMp, As, Bs, x * 128, s0, s1, t);
}

// ---------------------------------------------------------------------------
// Pool (8 lanes per (roi,bin)): lane j in 0..7.
// Stage 1: corner c=j&3, map m=j>>2 -> ONE half8 load each; butterfly xor
// 1,2 (sum corners within map) then xor 4 (add other map's split-K partial)
// -> full o[8]. Stage 2: group g=j&3, y-half h=j>>2 -> TWO half2 loads each;
// xor 4 combines halves. Lane j<4 writes ch 2g, j>=4 writes ch 2g+1.
// ---------------------------------------------------------------------------
__device__ __forceinline__ void bilin_setup(float y, float x,
                                            int& iy0, int& iy1, int& ix0, int& ix1,
                                            float& w00, float& w01, float& w10, float& w11) {
  const float y0f = floorf(y), x0f = floorf(x);
  const float wy = y - y0f, wx = x - x0f;   // unclamped, matches reference
  const int a = (int)y0f, b = (int)x0f;
  iy0 = min(max(a, 0), HH - 1);
  iy1 = min(max(a + 1, 0), HH - 1);
  ix0 = min(max(b, 0), WW - 1);
  ix1 = min(max(b + 1, 0), WW - 1);
  w00 = (1.f - wy) * (1.f - wx);
  w01 = (1.f - wy) * wx;
  w10 = wy * (1.f - wx);
  w11 = wy * wx;
}

__device__ __forceinline__ void pool_item8(const _Float16* __restrict__ Fh,
                                           const float* __restrict__ R,
                                           const _Float16* __restrict__ OMa,
                                           const _Float16* __restrict__ OMb,
                                           float* __restrict__ out, int tid) {
  const int j  = tid & 7;          // lane role within (roi,bin)
  const int nb = tid >> 3;
  const int n  = nb / NBIN;
  const int b  = nb - n * NBIN;
  const int bi = b / PSK;
  const int bj = b - bi * PSK;

  const float rx1 = R[n * 5 + 1], ry1 = R[n * 5 + 2];
  const float rx2 = R[n * 5 + 3], ry2 = R[n * 5 + 4];
  const float x1 = rx1 * (1.f / 16.f);
  const float y1 = ry1 * (1.f / 16.f);
  const float x2 = (rx2 + 1.f) * (1.f / 16.f);
  const float y2 = (ry2 + 1.f) * (1.f / 16.f);
  const float bw = (x2 - x1) * (1.f / 7.f);
  const float bh = (y2 - y1) * (1.f / 7.f);
  const float cx = x1 + ((float)bj + 0.5f) * bw;
  const float cy = y1 + ((float)bi + 0.5f) * bh;
  const float sxs = (rx2 - rx1 + 1.f) * (LAMDA / 16.f);
  const float sys = (ry2 - ry1 + 1.f) * (LAMDA / 16.f);

  // ---- stage 1: lane = (corner j&3, map j>>2); one half8 load ----
  int iy0, iy1, ix0, ix1;
  float w00, w01, w10, w11;
  bilin_setup(cy, cx, iy0, iy1, ix0, ix1, w00, w01, w10, w11);

  const int c = j & 3;
  const int cyi = (c >> 1) ? iy1 : iy0;
  const int cxi = (c & 1) ? ix1 : ix0;
  const float wq = (c == 0) ? w00 : (c == 1) ? w01 : (c == 2) ? w10 : w11;

  const _Float16* OMp = (j >> 2) ? OMb : OMa;
  const size_t base = (size_t)(cyi * WW + cxi) * CC + (size_t)b * 8;
  const half8 hv = *(const half8*)(OMp + base);

  float o8[8];
#pragma unroll
  for (int i = 0; i < 8; ++i) o8[i] = wq * (float)hv[i];
#pragma unroll
  for (int i = 0; i < 8; ++i) o8[i] += __shfl_xor(o8[i], 1);
#pragma unroll
  for (int i = 0; i < 8; ++i) o8[i] += __shfl_xor(o8[i], 2);
#pragma unroll
  for (int i = 0; i < 8; ++i) o8[i] += __shfl_xor(o8[i], 4);

  const int g = j & 3;
  const float sx = cx + o8[2 * g] * sxs;
  const float sy = cy + o8[2 * g + 1] * sys;

  // ---- stage 2: lane = (group g, y-half j>>2); two half2 loads ----
  int jy0, jy1, jx0, jx1;
  float u00, u01, u10, u11;
  bilin_setup(sy, sx, jy0, jy1, jx0, jx1, u00, u01, u10, u11);

  const int  yh = j >> 2;
  const int  jy = yh ? jy1 : jy0;
  const float ua = yh ? u10 : u00;   // weight at (jy, jx0)
  const float ub = yh ? u11 : u01;   // weight at (jy, jx1)

  const size_t c0 = (size_t)b * 8 + 2 * g;
  const half2v qa = *(const half2v*)(Fh + ((size_t)(jy + 1) * HPAD + (jx0 + 1)) * CPAD + c0);
  const half2v qb = *(const half2v*)(Fh + ((size_t)(jy + 1) * HPAD + (jx1 + 1)) * CPAD + c0);

  float v0 = ua * (float)qa[0] + ub * (float)qb[0];
  float v1 = ua * (float)qa[1] + ub * (float)qb[1];
  v0 += __shfl_xor(v0, 4);
  v1 += __shfl_xor(v1, 4);

  // lane j<4 writes channel 2g, lane j>=4 writes channel 2g+1 (one store each)
  const float vout = yh ? v1 : v0;
  out[((size_t)n * 8 + 2 * g + yh) * NBIN + b] = vout;
}

// ---------------------------------------------------------------------------
// Cooperative kernel: prep -> grid.sync -> split-K conv -> grid.sync -> pool.
// Conv phase is the R2-verified structure verbatim (150.8 us best). The pool
// fusion only removes a kernel launch + dispatch gap.
// ---------------------------------------------------------------------------
__global__ __launch_bounds__(NTHR, 4)
void mega_kernel(const float* __restrict__ F, const float* __restrict__ Wt,
                 const float* __restrict__ R,
                 _Float16* __restrict__ OMa, _Float16* __restrict__ OMb,
                 _Float16* __restrict__ Fh, _Float16* __restrict__ Bth,
                 float* __restrict__ out) {
  __shared__ __align__(16) _Float16 smem[ATH + BTH];  // 33.8 KB -> 4 blocks/CU
  const int bid = blockIdx.x;
  const int t = threadIdx.x;
  cg::grid_group grid = cg::this_grid();

  prep_features(F, Fh, bid * NTHR + t, GSTRIDE);
  prep_weights(Wt, Bth, (float(*)[33])smem, bid, t, NBLK);

  __threadfence();
  grid.sync();

  conv_dispatch(Fh, Bth, OMa, OMb, smem, smem + ATH, bid, t);

  __threadfence();
  grid.sync();

  for (int idx = bid * NTHR + t; idx < POOL8; idx += GSTRIDE)
    pool_item8(Fh, R, OMa, OMb, out, idx);
}

__global__ __launch_bounds__(256)
void pool_kernel(const _Float16* __restrict__ Fh, const float* __restrict__ R,
                 const _Float16* __restrict__ OMa, const _Float16* __restrict__ OMb,
                 float* __restrict__ out) {
  pool_item8(Fh, R, OMa, OMb, out, blockIdx.x * 256 + threadIdx.x);
}

// ---------------------------------------------------------------------------
// Non-coop fallback (same device code, separate launches)
// ---------------------------------------------------------------------------
__global__ __launch_bounds__(256)
void prep_kernel_sa(const float* __restrict__ F, const float* __restrict__ Wt,
                    _Float16* __restrict__ Fh, _Float16* __restrict__ Bth) {
  __shared__ float tile[32][33];
  prep_features(F, Fh, blockIdx.x * 256 + threadIdx.x, gridDim.x * 256);
  prep_weights(Wt, Bth, tile, blockIdx.x, threadIdx.x, gridDim.x);
}

__global__ __launch_bounds__(256, 4)
void conv_kernel_sa(const _Float16* __restrict__ Fh, const _Float16* __restrict__ Bth,
                    _Float16* __restrict__ OMa, _Float16* __restrict__ OMb) {
  __shared__ __align__(16) _Float16 smem[ATH + BTH];
  conv_dispatch(Fh, Bth, OMa, OMb, smem, smem + ATH, blockIdx.x, threadIdx.x);
}

extern "C" void kernel_launch(void* const* d_in, const int* in_sizes, int n_in,
                              void* d_out, int out_size, void* d_ws, size_t ws_size,
                              hipStream_t stream) {
  const float* F  = (const float*)d_in[0];   // features [1,128,128,392] fp32
  const float* R  = (const float*)d_in[1];   // rois [2048,5] fp32
  const float* Wt = (const float*)d_in[2];   // conv_w [3,3,392,392] fp32
  float* out = (float*)d_out;                // [2048,8,7,7] fp32

  const size_t omBytes  = (size_t)NPIX * CC * sizeof(_Float16);            // 12.85 MB
  const size_t fhBytes  = (size_t)HPAD * HPAD * CPAD * sizeof(_Float16);   // 15.14 MB
  // Bth: 416 * 4032 * 2B = 3.35 MB; total ~44.2 MB

  _Float16* OMa = (_Float16*)d_ws;
  _Float16* OMb = OMa + (size_t)NPIX * CC;
  _Float16* Fh  = (_Float16*)((char*)d_ws + 2 * omBytes);
  _Float16* Bth = (_Float16*)((char*)d_ws + 2 * omBytes + fhBytes);

  int maxBlk = 0;
  hipError_t qerr = hipOccupancyMaxActiveBlocksPerMultiprocessor(&maxBlk, mega_kernel, NTHR, 0);
  bool coopOk = (qerr == hipSuccess && maxBlk >= 4);

  if (coopOk) {
    void* args[] = {(void*)&F, (void*)&Wt, (void*)&R, (void*)&OMa, (void*)&OMb,
                    (void*)&Fh, (void*)&Bth, (void*)&out};
    hipError_t err = hipLaunchCooperativeKernel((const void*)mega_kernel,
                                                dim3(NBLK), dim3(NTHR),
                                                args, 0, stream);
    if (err != hipSuccess) {
      (void)hipGetLastError();
      coopOk = false;
    }
  }
  if (!coopOk) {
    prep_kernel_sa<<<2048, 256, 0, stream>>>(F, Wt, Fh, Bth);
    conv_kernel_sa<<<NBLK, 256, 0, stream>>>(Fh, Bth, OMa, OMb);
    pool_kernel<<<POOL8 / 256, 256, 0, stream>>>(Fh, R, OMa, OMb, out);
  }
}